// Round 3
// baseline (324.119 us; speedup 1.0000x reference)
//
#include <hip/hip_runtime.h>
#include <cstdint>
#include <cstddef>

// ---------------------------------------------------------------------------
// SparseConv3DBlock: BN(inference)+SiLU -> gather(27 neighbors) -> implicit GEMM
// N=200000, F_IN=64, F_OUT=128, K=27.  bf16 MFMA path.
//   k1: y_bf16[N][64] = silu(bn(x))
//   k2: Wt_bf16[27][128][64] = transpose(W)
//   k3: BARRIER-FREE: 1-wave blocks, wave owns 64 rows x 128 cols exclusively.
//       A-frags gathered straight into registers (lane map == MFMA A layout),
//       double-buffered one k-offset ahead; B from L1/L2-hot Wt. No LDS.
// ---------------------------------------------------------------------------

typedef __attribute__((ext_vector_type(8))) short short8;
typedef __attribute__((ext_vector_type(4))) float f32x4;

#define N_VOX 200000
#define F_IN 64
#define F_OUT 128
#define KOFF 27

__device__ __forceinline__ short f2bf(float f) {
  unsigned u = __builtin_bit_cast(unsigned, f);
  u += 0x7fffu + ((u >> 16) & 1u);   // RNE
  return (short)(u >> 16);
}

// ---------------- Kernel 1: BN + SiLU + cast to bf16 ----------------------
__global__ __launch_bounds__(256) void bn_silu_kernel(
    const float* __restrict__ x, const float* __restrict__ gamma,
    const float* __restrict__ beta, const float* __restrict__ mean,
    const float* __restrict__ var, short* __restrict__ y) {
  __shared__ float s_scale[F_IN], s_bias[F_IN];
  int tid = threadIdx.x;
  if (tid < F_IN) {
    float s = gamma[tid] * rsqrtf(var[tid] + 1e-5f);
    s_scale[tid] = s;
    s_bias[tid] = beta[tid] - mean[tid] * s;
  }
  __syncthreads();
  size_t i = ((size_t)blockIdx.x * 256 + tid) * 8;   // 12.8M total, exact
  int f0 = (int)(i & (F_IN - 1));                    // multiple of 8
  float4 x0 = *(const float4*)(x + i);
  float4 x1 = *(const float4*)(x + i + 4);
  float v[8] = {x0.x, x0.y, x0.z, x0.w, x1.x, x1.y, x1.z, x1.w};
  short8 o;
#pragma unroll
  for (int j = 0; j < 8; ++j) {
    float t = v[j] * s_scale[f0 + j] + s_bias[f0 + j];
    float sg = 1.0f / (1.0f + __expf(-t));
    o[j] = f2bf(t * sg);
  }
  *(short8*)(y + i) = o;
}

// ---------------- Kernel 2: W[27][64][128] f32 -> Wt[27][128][64] bf16 ----
__global__ __launch_bounds__(256) void wprep_kernel(
    const float* __restrict__ W, short* __restrict__ Wt) {
  int tid = blockIdx.x * 256 + threadIdx.x;        // 27*128*8 = 27648 threads
  if (tid >= KOFF * F_OUT * 8) return;
  int k = tid >> 10;                               // /(128*8)
  int r = tid & 1023;
  int o = r >> 3;
  int f0 = (r & 7) * 8;
  short8 vv;
#pragma unroll
  for (int i = 0; i < 8; ++i)
    vv[i] = f2bf(W[((size_t)k * F_IN + f0 + i) * F_OUT + o]);
  *(short8*)(Wt + ((size_t)k * F_OUT + o) * F_IN + f0) = vv;
}

// ---------------- Kernel 3: barrier-free gather + implicit GEMM -----------
// 1 wave per block. Wave owns rows [64*bid, 64*bid+64) x cols [0,128).
// acc[4 row-tiles][8 col-tiles] of 16x16 (f32x4 each) = 128 VGPR.
// Per k-offset: 4 idx loads (k+2 ahead), 8 A-gathers (k+1 ahead, straight to
// the MFMA A-fragment registers), 16 B loads (L1/L2-hot Wt), 64 MFMA.

__global__ __launch_bounds__(64, 2) void conv_mfma_kernel(
    const short* __restrict__ y,     // [N][64] bf16
    const short* __restrict__ Wt,    // [27][128][64] bf16
    const int* __restrict__ nidx,    // [N][27]
    float* __restrict__ out) {       // [N][128] f32
  const int lane = threadIdx.x;      // 0..63
  const int llo = lane & 15;
  const int lhi = lane >> 4;
  const int row0 = blockIdx.x * 64;
  // lane l serves rows rt*16 + llo; its idx stream starts here:
  const int* idxp = nidx + (size_t)(row0 + llo) * KOFF;

  f32x4 acc[4][8] = {};
  short8 a_a[4][2], a_b[4][2];       // A-frag double buffer (cur/next k)
  int i_a[4], i_b[4];                // idx double buffer

  // ---- prologue: gather A(0); preload idx(1) ----
  {
    int it[4];
#pragma unroll
    for (int rt = 0; rt < 4; ++rt) it[rt] = idxp[rt * 16 * KOFF + 0];
#pragma unroll
    for (int rt = 0; rt < 4; ++rt) i_a[rt] = idxp[rt * 16 * KOFF + 1];
#pragma unroll
    for (int rt = 0; rt < 4; ++rt)
#pragma unroll
      for (int kf = 0; kf < 2; ++kf)
        a_a[rt][kf] = *(const short8*)(y + (size_t)it[rt] * F_IN +
                                       kf * 32 + lhi * 8);
  }

  // body(K): uses ACUR=A(K); prefetches INXT=idx(K+2), ANXT=A(K+1) via ICUR.
#define CONV_BODY(K, ACUR, ANXT, ICUR, INXT)                                   \
  {                                                                            \
    if ((K) + 2 < KOFF) {                                                      \
      _Pragma("unroll")                                                        \
      for (int rt = 0; rt < 4; ++rt)                                           \
        INXT[rt] = idxp[rt * 16 * KOFF + (K) + 2];                             \
    }                                                                          \
    if ((K) + 1 < KOFF) {                                                      \
      _Pragma("unroll")                                                        \
      for (int rt = 0; rt < 4; ++rt)                                           \
        _Pragma("unroll")                                                      \
        for (int kf = 0; kf < 2; ++kf)                                         \
          ANXT[rt][kf] = *(const short8*)(y + (size_t)ICUR[rt] * F_IN +        \
                                          kf * 32 + lhi * 8);                  \
    }                                                                          \
    _Pragma("unroll")                                                          \
    for (int kf = 0; kf < 2; ++kf)                                             \
      _Pragma("unroll")                                                        \
      for (int ct = 0; ct < 8; ++ct) {                                         \
        short8 bfrag = *(const short8*)(Wt +                                   \
            ((size_t)(K) * F_OUT + ct * 16 + llo) * F_IN + kf * 32 + lhi * 8); \
        _Pragma("unroll")                                                      \
        for (int rt = 0; rt < 4; ++rt)                                         \
          acc[rt][ct] = __builtin_amdgcn_mfma_f32_16x16x32_bf16(               \
              ACUR[rt][kf], bfrag, acc[rt][ct], 0, 0, 0);                      \
      }                                                                        \
  }

  for (int k = 0; k < KOFF - 1; k += 2) {        // k = 0,2,...,24
    CONV_BODY(k, a_a, a_b, i_a, i_b);
    CONV_BODY(k + 1, a_b, a_a, i_b, i_a);
  }
  CONV_BODY(KOFF - 1, a_a, a_b, i_a, i_b);       // k = 26
#undef CONV_BODY

  // ---- epilogue: C/D layout col=lane&15, row=(lane>>4)*4+j ----
#pragma unroll
  for (int rt = 0; rt < 4; ++rt)
#pragma unroll
    for (int ct = 0; ct < 8; ++ct) {
      const size_t rbase =
          (size_t)(row0 + rt * 16 + lhi * 4) * F_OUT + ct * 16 + llo;
#pragma unroll
      for (int j = 0; j < 4; ++j)
        out[rbase + (size_t)j * F_OUT] = acc[rt][ct][j];
    }
}

// ---------------------------------------------------------------------------
extern "C" void kernel_launch(void* const* d_in, const int* in_sizes, int n_in,
                              void* d_out, int out_size, void* d_ws, size_t ws_size,
                              hipStream_t stream) {
  const float* x     = (const float*)d_in[0];
  const float* gamma = (const float*)d_in[1];
  const float* beta  = (const float*)d_in[2];
  const float* rmean = (const float*)d_in[3];
  const float* rvar  = (const float*)d_in[4];
  const float* W     = (const float*)d_in[5];
  const int*   nidx  = (const int*)d_in[6];
  float* out = (float*)d_out;

  // workspace layout
  short* y_bf16  = (short*)d_ws;                                      // 25.6 MB
  short* Wt_bf16 = (short*)((char*)d_ws + (size_t)N_VOX * F_IN * 2);  // 442 KB

  bn_silu_kernel<<<(N_VOX * F_IN) / (256 * 8), 256, 0, stream>>>(
      x, gamma, beta, rmean, rvar, y_bf16);

  wprep_kernel<<<(KOFF * F_OUT * 8 + 255) / 256, 256, 0, stream>>>(W, Wt_bf16);

  // 200000 = 3125 * 64: one wave per block, no tail.
  conv_mfma_kernel<<<N_VOX / 64, 64, 0, stream>>>(y_bf16, Wt_bf16, nidx, out);
}

// Round 5
// 165.654 us; speedup vs baseline: 1.9566x; 1.9566x over previous
//
#include <hip/hip_runtime.h>
#include <cstdint>
#include <cstddef>

// ---------------------------------------------------------------------------
// SparseConv3DBlock: BN(inference)+SiLU -> gather(27 neighbors) -> implicit GEMM
// N=200000, F_IN=64, F_OUT=128, K=27.  bf16 MFMA path.
//   k1: y_bf16[N][64] = silu(bn(x))
//   k2: Wt_bf16[27][128][64] = transpose(W)
//   k3: BM=128, 8 waves. T14 async-STAGE: phase k issues plain global_loads of
//       A(k+1) into REGISTERS at the top (compiler-tracked vmcnt), MFMAs k,
//       then ds_writes the regs into buf^1 (auto-wait lands here = full-phase
//       latency cover), one __syncthreads per phase. XOR swizzle on ds_write.
// ---------------------------------------------------------------------------

typedef __attribute__((ext_vector_type(8))) short short8;
typedef __attribute__((ext_vector_type(4))) float f32x4;

#define N_VOX 200000
#define F_IN 64
#define F_OUT 128
#define KOFF 27
#define BM 128

__device__ __forceinline__ short f2bf(float f) {
  unsigned u = __builtin_bit_cast(unsigned, f);
  u += 0x7fffu + ((u >> 16) & 1u);   // RNE
  return (short)(u >> 16);
}

// ---------------- Kernel 1: BN + SiLU + cast to bf16 ----------------------
__global__ __launch_bounds__(256) void bn_silu_kernel(
    const float* __restrict__ x, const float* __restrict__ gamma,
    const float* __restrict__ beta, const float* __restrict__ mean,
    const float* __restrict__ var, short* __restrict__ y) {
  __shared__ float s_scale[F_IN], s_bias[F_IN];
  int tid = threadIdx.x;
  if (tid < F_IN) {
    float s = gamma[tid] * rsqrtf(var[tid] + 1e-5f);
    s_scale[tid] = s;
    s_bias[tid] = beta[tid] - mean[tid] * s;
  }
  __syncthreads();
  size_t i = ((size_t)blockIdx.x * 256 + tid) * 8;   // 12.8M total, exact
  int f0 = (int)(i & (F_IN - 1));                    // multiple of 8
  float4 x0 = *(const float4*)(x + i);
  float4 x1 = *(const float4*)(x + i + 4);
  float v[8] = {x0.x, x0.y, x0.z, x0.w, x1.x, x1.y, x1.z, x1.w};
  short8 o;
#pragma unroll
  for (int j = 0; j < 8; ++j) {
    float t = v[j] * s_scale[f0 + j] + s_bias[f0 + j];
    float sg = 1.0f / (1.0f + __expf(-t));
    o[j] = f2bf(t * sg);
  }
  *(short8*)(y + i) = o;
}

// ---------------- Kernel 2: W[27][64][128] f32 -> Wt[27][128][64] bf16 ----
__global__ __launch_bounds__(256) void wprep_kernel(
    const float* __restrict__ W, short* __restrict__ Wt) {
  int tid = blockIdx.x * 256 + threadIdx.x;        // 27*128*8 = 27648 threads
  if (tid >= KOFF * F_OUT * 8) return;
  int k = tid >> 10;                               // /(128*8)
  int r = tid & 1023;
  int o = r >> 3;
  int f0 = (r & 7) * 8;
  short8 vv;
#pragma unroll
  for (int i = 0; i < 8; ++i)
    vv[i] = f2bf(W[((size_t)k * F_IN + f0 + i) * F_OUT + o]);
  *(short8*)(Wt + ((size_t)k * F_OUT + o) * F_IN + f0) = vv;
}

// ---------------- Kernel 3: reg-staged gather + implicit GEMM -------------
// BM=128 voxels/block, 512 threads = 8 waves. Wave w: rows 0..127 x cols
// [16w,16w+16): 8 row-tiles of 16x16, K=64 per k-offset (16 MFMA/phase).
// Phase k: global_load A(k+1)->regs + B(k+1)->regs; MFMA(k) from buf[k&1];
// ds_write A regs -> buf[(k&1)^1] (swizzled); __syncthreads.

__global__ __launch_bounds__(512, 4) void conv_mfma_kernel(
    const short* __restrict__ y,     // [N][64] bf16
    const short* __restrict__ Wt,    // [27][128][64] bf16
    const int* __restrict__ nidx,    // [N][27]
    float* __restrict__ out) {       // [N][128] f32
  __shared__ __align__(16) short Atile[2][BM * F_IN];   // 2 x 16 KB
  __shared__ int s_idx[BM * KOFF];                      // 13.5 KB

  const int tid = threadIdx.x;
  const int wave = tid >> 6;         // 0..7
  const int lane = tid & 63;
  const int lhi = lane >> 4;         // 0..3
  const int llo = lane & 15;
  const int row0 = blockIdx.x * BM;
  const int nval = (N_VOX - row0 < BM) ? (N_VOX - row0) : BM;

  // gather geometry: lane serves rows m0, m1 = m0+8, chunk c (16B units)
  const int m0 = wave * 16 + (lane >> 3);
  const int m1 = m0 + 8;
  const int c = lane & 7;
  // swizzled LDS byte offsets for ds_write (m1&7 == m0&7 so wr1 = wr0+1024)
  const int wr0 = m0 * 128 + ((c ^ (m0 & 7)) << 4);
  const int wr1 = wr0 + 1024;
  // B stream: wave's col slice, frag base
  const short* wtp = Wt + (size_t)(wave * 16 + llo) * F_IN + lhi * 8;

  // stage this block's neighbor indices (coalesced); pad tail rows with 0
  for (int i = tid; i < BM * KOFF; i += 512)
    s_idx[i] = (i < nval * KOFF) ? nidx[(size_t)row0 * KOFF + i] : 0;
  __syncthreads();

  f32x4 acc[8] = {};
  short8 b0[2], b1[2];

  // ---- prologue: stage A(0) via regs -> buf0; load B(0) ----
  {
    const int g0 = s_idx[m0 * KOFF], g1 = s_idx[m1 * KOFF];
    short8 ar0 = *(const short8*)(y + (size_t)g0 * F_IN + c * 8);
    short8 ar1 = *(const short8*)(y + (size_t)g1 * F_IN + c * 8);
    b0[0] = *(const short8*)(wtp);
    b0[1] = *(const short8*)(wtp + 32);
    *(short8*)((char*)Atile[0] + wr0) = ar0;
    *(short8*)((char*)Atile[0] + wr1) = ar1;
  }
  __syncthreads();

#define CONV_BODY(K, BUF, BCUR, BNEXT)                                         \
  {                                                                            \
    short8 ar0, ar1;                                                           \
    if ((K) + 1 < KOFF) {                                                      \
      const int g0 = s_idx[m0 * KOFF + (K) + 1];                               \
      const int g1 = s_idx[m1 * KOFF + (K) + 1];                               \
      ar0 = *(const short8*)(y + (size_t)g0 * F_IN + c * 8);                   \
      ar1 = *(const short8*)(y + (size_t)g1 * F_IN + c * 8);                   \
      (BNEXT)[0] = *(const short8*)(wtp + (size_t)((K) + 1) * 8192);           \
      (BNEXT)[1] = *(const short8*)(wtp + (size_t)((K) + 1) * 8192 + 32);      \
    }                                                                          \
    _Pragma("unroll")                                                          \
    for (int rt = 0; rt < 8; ++rt) {                                           \
      const int mm = rt * 16 + llo;                                            \
      const int base = mm * 128 + lhi * 16;                                    \
      const int swz = (mm & 7) << 4;                                           \
      short8 a0 = *(const short8*)((const char*)Atile[BUF] + (base ^ swz));    \
      short8 a1 =                                                              \
          *(const short8*)((const char*)Atile[BUF] + ((base + 64) ^ swz));     \
      acc[rt] = __builtin_amdgcn_mfma_f32_16x16x32_bf16(a0, (BCUR)[0],         \
                                                        acc[rt], 0, 0, 0);     \
      acc[rt] = __builtin_amdgcn_mfma_f32_16x16x32_bf16(a1, (BCUR)[1],         \
                                                        acc[rt], 0, 0, 0);     \
    }                                                                          \
    __builtin_amdgcn_sched_barrier(0); /* keep ds_writes after MFMAs */        \
    if ((K) + 1 < KOFF) {                                                      \
      *(short8*)((char*)Atile[(BUF) ^ 1] + wr0) = ar0;                         \
      *(short8*)((char*)Atile[(BUF) ^ 1] + wr1) = ar1;                         \
    }                                                                          \
    __syncthreads();                                                           \
  }

  for (int k = 0; k < KOFF - 1; k += 2) {        // k = 0,2,...,24
    CONV_BODY(k, 0, b0, b1);
    CONV_BODY(k + 1, 1, b1, b0);
  }
  CONV_BODY(KOFF - 1, 0, b0, b1);                // k = 26 (buf 0)
#undef CONV_BODY

  // ---- epilogue: C/D layout col=lane&15, row=(lane>>4)*4+j ----
#pragma unroll
  for (int rt = 0; rt < 8; ++rt) {
    const int col = wave * 16 + llo;
    const int rbase = row0 + rt * 16 + lhi * 4;
#pragma unroll
    for (int j = 0; j < 4; ++j) {
      const int row = rbase + j;
      if (row < N_VOX) out[(size_t)row * F_OUT + col] = acc[rt][j];
    }
  }
}

// ---------------------------------------------------------------------------
extern "C" void kernel_launch(void* const* d_in, const int* in_sizes, int n_in,
                              void* d_out, int out_size, void* d_ws, size_t ws_size,
                              hipStream_t stream) {
  const float* x     = (const float*)d_in[0];
  const float* gamma = (const float*)d_in[1];
  const float* beta  = (const float*)d_in[2];
  const float* rmean = (const float*)d_in[3];
  const float* rvar  = (const float*)d_in[4];
  const float* W     = (const float*)d_in[5];
  const int*   nidx  = (const int*)d_in[6];
  float* out = (float*)d_out;

  // workspace layout
  short* y_bf16  = (short*)d_ws;                                      // 25.6 MB
  short* Wt_bf16 = (short*)((char*)d_ws + (size_t)N_VOX * F_IN * 2);  // 442 KB

  bn_silu_kernel<<<(N_VOX * F_IN) / (256 * 8), 256, 0, stream>>>(
      x, gamma, beta, rmean, rvar, y_bf16);

  wprep_kernel<<<(KOFF * F_OUT * 8 + 255) / 256, 256, 0, stream>>>(W, Wt_bf16);

  conv_mfma_kernel<<<(N_VOX + BM - 1) / BM, 512, 0, stream>>>(
      y_bf16, Wt_bf16, nidx, out);
}